// Round 10
// baseline (280.396 us; speedup 1.0000x reference)
//
#include <hip/hip_runtime.h>
#include <hip/hip_bf16.h>

#define N_USERS 100000
#define M_ITEMS 200000
#define N_NODES 300000   // N_USERS + M_ITEMS
#define N_EDGES 1200000
#define BATCH   4096
#define NB      ((N_NODES + 255) / 256)   // 1172
#define CHUNK   5                          // ceil(NB/256)
#define EPT8    (N_EDGES / 8)              // 150000: 8 edges per thread
#define EGRID8  ((EPT8 + 255) / 256)       // 586 blocks

typedef __attribute__((ext_vector_type(8))) short short8;
typedef __attribute__((ext_vector_type(4))) float floatx4;

static __device__ __forceinline__ float b2f(__hip_bfloat16 x) { return __bfloat162float(x); }

static __device__ __forceinline__ short f2bs(float f) {
    union { __hip_bfloat16 h; short s; } u;
    u.h = __float2bfloat16(f);   // RNE
    return u.s;
}
static __device__ __forceinline__ float us2f(unsigned int us) {
    return __uint_as_float(us << 16);
}

// dtype-adaptive input load: isbf chosen at runtime from device-side sniff
static __device__ __forceinline__ float loadf(const void* p, int i, int isbf) {
    if (isbf) return b2f(((const __hip_bfloat16*)p)[i]);
    return ((const float*)p)[i];
}

// vals is uniform[0,1). bf16 buffer: u16[even] upper byte in [0x3A,0x3F].
static __device__ __forceinline__ int sniff_dev(const void* vals) {
    const unsigned short* v16 = (const unsigned short*)vals;
    int c = 0;
#pragma unroll
    for (int i = 0; i < 16; ++i) {
        unsigned int ub = (v16[2 * i] >> 8) & 0xFF;
        if (ub >= 0x3A && ub <= 0x3F) ++c;
    }
    return (c >= 12) ? 1 : 0;
}

static __device__ __forceinline__ void unpack8(float* o, uint4 e) {
    unsigned int w[4] = {e.x, e.y, e.z, e.w};
#pragma unroll
    for (int j = 0; j < 8; ++j) o[j] = us2f((w[j >> 1] >> ((j & 1) * 16)) & 0xFFFFu);
}

// n64 = node*64 (premultiplied element offset)
static __device__ __forceinline__ const unsigned short* bfsrc(
    const void* ue, const void* ie, int n64) {
    return (n64 < N_USERS * 64)
        ? (const unsigned short*)ue + (size_t)(unsigned)n64
        : (const unsigned short*)ie + (size_t)(unsigned)(n64 - N_USERS * 64);
}
static __device__ __forceinline__ const float* fsrc(
    const void* ue, const void* ie, int n64) {
    return (n64 < N_USERS * 64)
        ? (const float*)ue + (size_t)(unsigned)n64
        : (const float*)ie + (size_t)(unsigned)(n64 - N_USERS * 64);
}

// 16 dims of a node row in A-fragment layout
static __device__ __forceinline__ void gather16o(
    float* o0, float* o1, const unsigned short* ego,
    const void* ue, const void* ie, int n64, int quad, int isbf, int use_src) {
    if (!use_src) {
        const unsigned short* p = ego + (size_t)(unsigned)n64 + quad * 8;
        unpack8(o0, *(const uint4*)p);
        unpack8(o1, *(const uint4*)(p + 32));
    } else if (isbf) {
        const unsigned short* p = bfsrc(ue, ie, n64) + quad * 8;
        unpack8(o0, *(const uint4*)p);
        unpack8(o1, *(const uint4*)(p + 32));
    } else {
        const float* p = fsrc(ue, ie, n64) + quad * 8;
        float4 a = *(const float4*)p;
        float4 b = *(const float4*)(p + 4);
        float4 c = *(const float4*)(p + 32);
        float4 d = *(const float4*)(p + 36);
        o0[0]=a.x; o0[1]=a.y; o0[2]=a.z; o0[3]=a.w; o0[4]=b.x; o0[5]=b.y; o0[6]=b.z; o0[7]=b.w;
        o1[0]=c.x; o1[1]=c.y; o1[2]=c.z; o1[3]=c.w; o1[4]=d.x; o1[5]=d.y; o1[6]=d.z; o1[7]=d.w;
    }
}

// ---------------- setup: wtrans (blocks 0..11) + frontier seed (blocks 12..43) ----------------
__global__ __launch_bounds__(256) void setup_kernel(
    const void* __restrict__ Wg, const void* __restrict__ bg,
    const void* __restrict__ Wb, const void* __restrict__ bb,
    const void* __restrict__ vals,
    const int* __restrict__ users, const int* __restrict__ items,
    unsigned short* __restrict__ WT, float* __restrict__ sb,
    unsigned char* __restrict__ f1, unsigned char* __restrict__ f2,
    unsigned char* __restrict__ f3) {
    if (blockIdx.x < 12) {
        int isbf = __builtin_amdgcn_readfirstlane(sniff_dev(vals));
        int t = blockIdx.x * 256 + threadIdx.x;
        if (t < 3072) {
            int lane = t & 63, h = (t >> 6) & 1, ct = (t >> 7) & 3, w = (t >> 9) & 1, k = t >> 10;
            int m = lane & 15, quad = lane >> 4;
            const void* Wsrc = w ? Wb : Wg;
#pragma unroll
            for (int j = 0; j < 8; ++j) {
                int kk = h * 32 + quad * 8 + j;
                WT[(size_t)(k * 1024 + w * 512 + ct * 128 + h * 64 + lane) * 8 + j] =
                    (unsigned short)f2bs(loadf(Wsrc, k * 4096 + kk * 64 + ct * 16 + m, isbf));
            }
        }
        if (t < 192) sb[t] = loadf(bg, t, isbf) + loadf(bb, t, isbf);
    } else {
        int i = (blockIdx.x - 12) * 256 + threadIdx.x;
        int n = -1;
        if (i < BATCH) n = users[i];
        else if (i < 2 * BATCH) n = N_USERS + items[i - BATCH];
        if (n >= 0) { f1[n] = 1; f2[n] = 1; f3[n] = 1; }
    }
}

// ---------------- frontier propagation (pure, no atomics; 8 edges/thread) ----------------
// 8 independent scattered byte-probes in flight per thread; cols loaded only on hit
// (prop1 ~90% of groups skip; prop2 ~57%).
__global__ __launch_bounds__(256) void prop_kernel(
    const int4* __restrict__ rows4, const int4* __restrict__ cols4,
    const unsigned char* __restrict__ src, unsigned char* __restrict__ dst) {
    int t = blockIdx.x * 256 + threadIdx.x;
    if (t < EPT8) {
        int4 ra = rows4[2 * t], rb = rows4[2 * t + 1];
        unsigned char s0 = src[ra.x], s1 = src[ra.y], s2 = src[ra.z], s3 = src[ra.w];
        unsigned char s4 = src[rb.x], s5 = src[rb.y], s6 = src[rb.z], s7 = src[rb.w];
        if (s0 | s1 | s2 | s3) {
            int4 c = cols4[2 * t];
            if (s0) dst[c.x] = 1;
            if (s1) dst[c.y] = 1;
            if (s2) dst[c.z] = 1;
            if (s3) dst[c.w] = 1;
        }
        if (s4 | s5 | s6 | s7) {
            int4 c = cols4[2 * t + 1];
            if (s4) dst[c.x] = 1;
            if (s5) dst[c.y] = 1;
            if (s6) dst[c.z] = 1;
            if (s7) dst[c.w] = 1;
        }
    }
}

// Degree count filtered by flag1 — atomic return value IS the within-row rank.
// 8 edges/thread; rank layout identical to the 4/thread version (uint2 per 4 edges).
__global__ __launch_bounds__(256) void count_rank_kernel(
    const int4* __restrict__ rows4, const unsigned char* __restrict__ flag1,
    int* __restrict__ off, uint2* __restrict__ rank) {
    int t = blockIdx.x * 256 + threadIdx.x;
    if (t < EPT8) {
        int4 ra = rows4[2 * t], rb = rows4[2 * t + 1];
        unsigned int k0 = 0xFFFFu, k1 = 0xFFFFu, k2 = 0xFFFFu, k3 = 0xFFFFu;
        unsigned int k4 = 0xFFFFu, k5 = 0xFFFFu, k6 = 0xFFFFu, k7 = 0xFFFFu;
        if (flag1[ra.x]) k0 = (unsigned int)atomicAdd(&off[ra.x + 1], 1);
        if (flag1[ra.y]) k1 = (unsigned int)atomicAdd(&off[ra.y + 1], 1);
        if (flag1[ra.z]) k2 = (unsigned int)atomicAdd(&off[ra.z + 1], 1);
        if (flag1[ra.w]) k3 = (unsigned int)atomicAdd(&off[ra.w + 1], 1);
        if (flag1[rb.x]) k4 = (unsigned int)atomicAdd(&off[rb.x + 1], 1);
        if (flag1[rb.y]) k5 = (unsigned int)atomicAdd(&off[rb.y + 1], 1);
        if (flag1[rb.z]) k6 = (unsigned int)atomicAdd(&off[rb.z + 1], 1);
        if (flag1[rb.w]) k7 = (unsigned int)atomicAdd(&off[rb.w + 1], 1);
        rank[2 * t]     = make_uint2((k0 & 0xFFFFu) | (k1 << 16), (k2 & 0xFFFFu) | (k3 << 16));
        rank[2 * t + 1] = make_uint2((k4 & 0xFFFFu) | (k5 << 16), (k6 & 0xFFFFu) | (k7 << 16));
    }
}

static __device__ __forceinline__ int deg_class(int d) {
    return d >= 16 ? 0 : d >= 8 ? 1 : d >= 4 ? 2 : 3;
}

// ---------------- fused scan A: per-block degree sums + 12-level class counts + cls bytes ----
// Class-mask restructure: 4 class ballots ONCE + 1 flag ballot per level.
__global__ __launch_bounds__(256) void scanA_kernel(
    const int* __restrict__ off, const unsigned char* __restrict__ flags,
    int* __restrict__ bsum, int* __restrict__ bcnt, unsigned char* __restrict__ cls) {
    __shared__ int s[256];
    __shared__ int wc[4][4];   // [wave][class]
    int t = threadIdx.x;
    int n = blockIdx.x * 256 + t;
    bool ir = (n < N_NODES);
    int deg = ir ? off[n + 1] : 0;      // raw degrees (pre-scan)
    s[t] = deg;
    __syncthreads();
    for (int o = 128; o >= 1; o >>= 1) {
        if (t < o) s[t] += s[t + o];
        __syncthreads();
    }
    if (t == 0) bsum[blockIdx.x] = s[0];
    int c = deg_class(deg);
    if (ir) cls[n] = (unsigned char)c;   // cls persisted: scanC must not re-read off
    int lane = t & 63;
    int wid  = t >> 6;
    unsigned long long mc[4];
#pragma unroll
    for (int cc = 0; cc < 4; ++cc) mc[cc] = __ballot(ir && (c == cc));
#pragma unroll
    for (int L = 0; L < 3; ++L) {
        unsigned long long mf = __ballot(ir && flags[L * N_NODES + n]);
        if (lane == 0) {
#pragma unroll
            for (int cc = 0; cc < 4; ++cc) wc[wid][cc] = __popcll(mf & mc[cc]);
        }
        __syncthreads();
        if (t < 4)
            bcnt[(L * 4 + t) * NB + blockIdx.x] = wc[0][t] + wc[1][t] + wc[2][t] + wc[3][t];
        __syncthreads();
    }
}

// ---------------- parallel top-scans: 13 concurrent blocks ----------------
// Blocks 0..11: one class row of bcnt each (per-row positions from 0; totals -> vtot).
// Block 12: bsum (degree block sums).
__global__ __launch_bounds__(256) void scanB13_kernel(
    int* __restrict__ bsum, int* __restrict__ bcnt, int* __restrict__ vtot) {
    __shared__ int s[256];
    int t = threadIdx.x;
    int* A = (blockIdx.x < 12) ? (bcnt + (size_t)blockIdx.x * NB) : bsum;
    int base = t * CHUNK, loc = 0;
    for (int j = 0; j < CHUNK; ++j) { int i = base + j; if (i < NB) loc += A[i]; }
    s[t] = loc;
    __syncthreads();
    for (int o = 1; o < 256; o <<= 1) {
        int add = (t >= o) ? s[t - o] : 0;
        __syncthreads();
        s[t] += add;
        __syncthreads();
    }
    int run = (t == 0) ? 0 : s[t - 1];
    for (int j = 0; j < CHUNK; ++j) {
        int i = base + j;
        if (i < NB) { int tmp = A[i]; A[i] = run; run += tmp; }
    }
    if (blockIdx.x < 12 && t == 0) vtot[blockIdx.x] = s[255];
}

// ---------------- fused scan C: off scan + 12-level scatter (+ map3, cnts) ----------------
// Class base within level (vb) folded in from vtot; class-mask scatter.
__global__ __launch_bounds__(256) void scanC_kernel(
    int* __restrict__ off, const int* __restrict__ bsum,
    const unsigned char* __restrict__ flags, const unsigned char* __restrict__ cls,
    const int* __restrict__ bcnt, const int* __restrict__ vtot,
    int* __restrict__ lists, int* __restrict__ map3, int* __restrict__ cnts) {
    __shared__ int s[256];
    __shared__ int wc[4][4];
    __shared__ int vb[12];
    int t = threadIdx.x;
    if (t < 12) {
        int L = t >> 2, c = t & 3;
        int b = 0;
        for (int cc = 0; cc < c; ++cc) b += vtot[L * 4 + cc];
        vb[t] = b;
    }
    if (blockIdx.x == 0 && t < 3)
        cnts[t] = vtot[t * 4] + vtot[t * 4 + 1] + vtot[t * 4 + 2] + vtot[t * 4 + 3];
    int n = blockIdx.x * 256 + t;
    bool ir = (n < N_NODES);
    s[t] = ir ? off[n + 1] : 0;
    __syncthreads();   // covers vb writes too
    for (int o = 1; o < 256; o <<= 1) {
        int add = (t >= o) ? s[t - o] : 0;
        __syncthreads();
        s[t] += add;
        __syncthreads();
    }
    if (ir) off[n + 1] = s[t] + bsum[blockIdx.x];
    int c = ir ? (int)cls[n] : 3;
    int lane = t & 63;
    int wid  = t >> 6;
    unsigned long long mc[4];
#pragma unroll
    for (int cc = 0; cc < 4; ++cc) mc[cc] = __ballot(ir && (c == cc));
    unsigned long long lt = (1ull << lane) - 1ull;
#pragma unroll
    for (int L = 0; L < 3; ++L) {
        bool fl = ir && flags[L * N_NODES + n];
        unsigned long long mf = __ballot(fl);
        if (lane == 0) {
#pragma unroll
            for (int cc = 0; cc < 4; ++cc) wc[wid][cc] = __popcll(mf & mc[cc]);
        }
        __syncthreads();
        if (fl) {
            int wpre = 0;
            for (int i = 0; i < wid; ++i) wpre += wc[i][c];
            int pos = bcnt[(L * 4 + c) * NB + blockIdx.x] + vb[L * 4 + c] + wpre
                    + __popcll(mf & mc[c] & lt);
            lists[L * N_NODES + pos] = n;
            if (L == 2) map3[n] = pos + 1;   // node -> compact batch-acc slot (+1; 0 = none)
        }
        __syncthreads();
    }
}

// ---------------- atomic-free fill: p = off[row] + rank[e]; stores col<<6 (8 edges/thread) ----
__global__ __launch_bounds__(256) void fill_kernel(
    const int4* __restrict__ rows4, const int4* __restrict__ cols4,
    const void* __restrict__ vals, const int* __restrict__ off,
    const uint2* __restrict__ rank, int2* __restrict__ epack) {
    int isbf = __builtin_amdgcn_readfirstlane(sniff_dev(vals));
    int t = blockIdx.x * 256 + threadIdx.x;
    if (t < EPT8) {
        int4 ra = rows4[2 * t], rb = rows4[2 * t + 1];
        int4 ca = cols4[2 * t], cb = cols4[2 * t + 1];
        uint2 ka = rank[2 * t], kb = rank[2 * t + 1];
        unsigned int k0 = ka.x & 0xFFFFu, k1 = ka.x >> 16, k2 = ka.y & 0xFFFFu, k3 = ka.y >> 16;
        unsigned int k4 = kb.x & 0xFFFFu, k5 = kb.x >> 16, k6 = kb.y & 0xFFFFu, k7 = kb.y >> 16;
        int e = t * 8;
        if (k0 != 0xFFFFu)
            epack[off[ra.x] + (int)k0] = make_int2(ca.x << 6, __float_as_int(loadf(vals, e, isbf)));
        if (k1 != 0xFFFFu)
            epack[off[ra.y] + (int)k1] = make_int2(ca.y << 6, __float_as_int(loadf(vals, e + 1, isbf)));
        if (k2 != 0xFFFFu)
            epack[off[ra.z] + (int)k2] = make_int2(ca.z << 6, __float_as_int(loadf(vals, e + 2, isbf)));
        if (k3 != 0xFFFFu)
            epack[off[ra.w] + (int)k3] = make_int2(ca.w << 6, __float_as_int(loadf(vals, e + 3, isbf)));
        if (k4 != 0xFFFFu)
            epack[off[rb.x] + (int)k4] = make_int2(cb.x << 6, __float_as_int(loadf(vals, e + 4, isbf)));
        if (k5 != 0xFFFFu)
            epack[off[rb.y] + (int)k5] = make_int2(cb.y << 6, __float_as_int(loadf(vals, e + 5, isbf)));
        if (k6 != 0xFFFFu)
            epack[off[rb.z] + (int)k6] = make_int2(cb.z << 6, __float_as_int(loadf(vals, e + 6, isbf)));
        if (k7 != 0xFFFFu)
            epack[off[rb.w] + (int)k7] = make_int2(cb.w << 6, __float_as_int(loadf(vals, e + 7, isbf)));
    }
}

// ---------------- Fused SpMM + Transform (per layer), no LDS ----------------
// Best-measured config (R9: 52.0us, VGPR 72): 64-thread (1-wave) blocks, static
// interleaved tiles, NON-unrolled edge loop, PRELOADED B-fragments. Layer 0
// (USE_SRC) STORES acc (each compact slot written exactly once in L0 since
// flag3 ⊆ flag1) so acc needs no memset; L1/L2 accumulate.
template<int USE_SRC>
__global__ __launch_bounds__(64) void fused_layer_kernel(
    const int* __restrict__ off, const int2* __restrict__ epack,
    const unsigned short* __restrict__ ego_in,
    const void* __restrict__ ue, const void* __restrict__ ie,
    const void* __restrict__ vals,
    const unsigned short* __restrict__ WT, const float* __restrict__ sb,
    int klayer, unsigned short* __restrict__ ego_out,
    const int* __restrict__ list, const int* __restrict__ cntp,
    const int* __restrict__ map3, float* __restrict__ acc) {
    const int isbf = USE_SRC ? __builtin_amdgcn_readfirstlane(sniff_dev(vals)) : 0;
    const int cnt  = __builtin_amdgcn_readfirstlane(cntp[0]);
    const int ntile = (cnt + 15) >> 4;
    const int wv = blockIdx.x;
    const int nw = gridDim.x;
    if (wv >= ntile) return;            // dead blocks exit before the prologue
    const int lane = threadIdx.x;
    const int m    = lane & 15;
    const int quad = lane >> 4;

    const unsigned short* wt = WT + (size_t)klayer * 8192;
    short8 Bg[4][2], Bb[4][2];
#pragma unroll
    for (int ct = 0; ct < 4; ++ct)
#pragma unroll
        for (int h = 0; h < 2; ++h) {
            Bg[ct][h] = *(const short8*)(wt + (size_t)((ct * 2 + h) * 64 + lane) * 8);
            Bb[ct][h] = *(const short8*)(wt + (size_t)(512 + (ct * 2 + h) * 64 + lane) * 8);
        }
    float bv[4];
#pragma unroll
    for (int ct = 0; ct < 4; ++ct) bv[ct] = sb[klayer * 64 + ct * 16 + m];

    for (int tile = wv; tile < ntile; tile += nw) {
        const int idx = tile * 16 + m;
        const int row = list[idx < cnt ? idx : cnt - 1];
        const int start = off[row];
        const int end   = off[row + 1];

        float eg0[8], eg1[8];
        gather16o(eg0, eg1, ego_in, ue, ie, row << 6, quad, isbf, USE_SRC);

        float s0[8] = {0,0,0,0,0,0,0,0};
        float s1[8] = {0,0,0,0,0,0,0,0};
        for (int e = start; e < end; ++e) {
            int2 cv = epack[e];
            float v = __int_as_float(cv.y);
            float t0[8], t1[8];
            gather16o(t0, t1, ego_in, ue, ie, cv.x, quad, isbf, USE_SRC);
#pragma unroll
            for (int j = 0; j < 8; ++j) {
                s0[j] = fmaf(v, t0[j], s0[j]);
                s1[j] = fmaf(v, t1[j], s1[j]);
            }
        }

        short8 As0, As1, Ap0, Ap1;
#pragma unroll
        for (int j = 0; j < 8; ++j) {
            As0[j] = f2bs(s0[j]);
            As1[j] = f2bs(s1[j]);
            Ap0[j] = f2bs(eg0[j] * s0[j]);
            Ap1[j] = f2bs(eg1[j] * s1[j]);
        }

        floatx4 accf[4];
#pragma unroll
        for (int ct = 0; ct < 4; ++ct) {
            floatx4 a = {0.f, 0.f, 0.f, 0.f};
            a = __builtin_amdgcn_mfma_f32_16x16x32_bf16(As0, Bg[ct][0], a, 0, 0, 0);
            a = __builtin_amdgcn_mfma_f32_16x16x32_bf16(As1, Bg[ct][1], a, 0, 0, 0);
            a = __builtin_amdgcn_mfma_f32_16x16x32_bf16(Ap0, Bb[ct][0], a, 0, 0, 0);
            a = __builtin_amdgcn_mfma_f32_16x16x32_bf16(Ap1, Bb[ct][1], a, 0, 0, 0);
            accf[ct] = a;
        }

        float v[4][4];
        float ssq[4] = {0.f, 0.f, 0.f, 0.f};
#pragma unroll
        for (int ct = 0; ct < 4; ++ct)
#pragma unroll
            for (int r = 0; r < 4; ++r) {
                float x = accf[ct][r] + bv[ct];
                x = x > 0.f ? x : 0.2f * x;           // leaky_relu(0.2)
                v[ct][r] = x;
                ssq[r] += x * x;
            }
#pragma unroll
        for (int o = 1; o < 16; o <<= 1)
#pragma unroll
            for (int r = 0; r < 4; ++r) ssq[r] += __shfl_xor(ssq[r], o, 64);
#pragma unroll
        for (int r = 0; r < 4; ++r) {
            int idx_w = tile * 16 + quad * 4 + r;
            if (idx_w < cnt) {
                float sc = 1.0f / fmaxf(sqrtf(ssq[r]), 1e-12f);
                int rw = list[idx_w];
                int c3 = map3[rw];
#pragma unroll
                for (int ct = 0; ct < 4; ++ct)
                    ego_out[(size_t)rw * 64 + ct * 16 + m] = (unsigned short)f2bs(v[ct][r] * sc);
                if (c3 > 0) {
                    float* ap = acc + (size_t)(c3 - 1) * 64 + m;
                    if (USE_SRC) {
#pragma unroll
                        for (int ct = 0; ct < 4; ++ct) ap[ct * 16] = v[ct][r] * sc;
                    } else {
#pragma unroll
                        for (int ct = 0; ct < 4; ++ct) ap[ct * 16] += v[ct][r] * sc;
                    }
                }
            }
        }
    }
}

// out[b] = dot(acc_u + ego0_u, acc_i + ego0_i) / 16   (acc read via map3)
__global__ __launch_bounds__(256) void dot_kernel(
    const int* __restrict__ users, const int* __restrict__ items,
    const float* __restrict__ acc, const int* __restrict__ map3,
    const void* __restrict__ ue, const void* __restrict__ ie,
    void* __restrict__ out, const void* __restrict__ vals) {
    int isbf = __builtin_amdgcn_readfirstlane(sniff_dev(vals));
    int gid = blockIdx.x * 256 + threadIdx.x;
    int b = gid >> 6;
    int lane = gid & 63;
    int un = __builtin_amdgcn_readfirstlane(users[b]);
    int in_ = __builtin_amdgcn_readfirstlane(items[b]);
    int cu = __builtin_amdgcn_readfirstlane(map3[un]);
    int ci = __builtin_amdgcn_readfirstlane(map3[N_USERS + in_]);
    float u = (cu > 0 ? acc[(size_t)(cu - 1) * 64 + lane] : 0.f) + loadf(ue, un * 64 + lane, isbf);
    float v = (ci > 0 ? acc[(size_t)(ci - 1) * 64 + lane] : 0.f) + loadf(ie, in_ * 64 + lane, isbf);
    float pr = u * v;
#pragma unroll
    for (int o = 32; o >= 1; o >>= 1) pr += __shfl_xor(pr, o, 64);
    if (lane == 0) {
        float r = pr * 0.0625f;
        if (isbf) ((__hip_bfloat16*)out)[b] = __float2bfloat16(r);
        else      ((float*)out)[b] = r;
    }
}

static inline size_t align16(size_t x) { return (x + 15) & ~(size_t)15; }

extern "C" void kernel_launch(void* const* d_in, const int* in_sizes, int n_in,
                              void* d_out, int out_size, void* d_ws, size_t ws_size,
                              hipStream_t stream) {
    const int* users = (const int*)d_in[0];
    const int* items = (const int*)d_in[1];
    const int* rows  = (const int*)d_in[2];
    const int* cols  = (const int*)d_in[3];
    const void* vals     = d_in[4];
    const void* user_emb = d_in[5];
    const void* item_emb = d_in[6];
    const void* W_gc     = d_in[7];
    const void* b_gc     = d_in[8];
    const void* W_bi     = d_in[9];
    const void* b_bi     = d_in[10];

    const size_t egoB   = (size_t)N_NODES * 64 * sizeof(short);   // 38.4 MB (x2)
    const size_t packB  = (size_t)N_EDGES * sizeof(int2);         // 9.6 MB
    const size_t rankB  = (size_t)(N_EDGES / 4) * sizeof(uint2);  // 2.4 MB (u16 ranks)
    const size_t bsumB  = (size_t)NB * sizeof(int);
    const size_t bcntB  = (size_t)12 * NB * sizeof(int);          // 12 virtual levels
    const size_t clsB   = (size_t)N_NODES;                        // degree-class bytes
    const size_t wtB    = (size_t)3 * 1024 * 8 * sizeof(short);   // 49 KB
    const size_t sbB    = (size_t)192 * sizeof(float);
    const size_t accB   = (size_t)2 * BATCH * 64 * sizeof(float); // 2 MB (L0 stores; no memset)
    const size_t offB   = (size_t)(N_NODES + 1) * sizeof(int);
    const size_t cntsB  = (size_t)32 * sizeof(int);               // cnts(3) | vtot(12)@+4
    const size_t map3B  = (size_t)N_NODES * sizeof(int);
    const size_t flagsB = (size_t)3 * N_NODES;                    // 0.9 MB (bytes)

    char* ws = (char*)d_ws;
    size_t o = 0;
    unsigned short* egoA  = (unsigned short*)(ws + o); o += egoB;
    unsigned short* egoB2 = (unsigned short*)(ws + o); o += egoB;
    int2*  epack  = (int2*)(ws + o);  o += packB;
    uint2* rank   = (uint2*)(ws + o); o += rankB;
    int*   bsum   = (int*)(ws + o);   o += bsumB;
    int*   bcnt   = (int*)(ws + o);   o += bcntB;
    unsigned char* cls = (unsigned char*)(ws + o); o += clsB;
    o = align16(o);
    unsigned short* WT = (unsigned short*)(ws + o); o += wtB;
    float* sb     = (float*)(ws + o); o += sbB;
    o = align16(o);
    float* acc    = (float*)(ws + o); o += accB;      // outside zero region (L0 stores)
    // contiguous zero-region: off | cnts(32) | map3 | flags(bytes)
    int*   off    = (int*)(ws + o);
    int*   cnts   = (int*)((char*)off + offB);
    int*   vtot   = cnts + 4;
    int*   map3   = (int*)((char*)cnts + cntsB);
    unsigned char* flags = (unsigned char*)((char*)map3 + map3B);
    const size_t zeroB = offB + cntsB + map3B + flagsB;
    unsigned char* flagL[3] = {flags, flags + N_NODES, flags + 2 * N_NODES};
    int* lists = (int*)(flags + flagsB);   // flagsB divisible by 4
    int* listL[3] = {lists, lists + N_NODES, lists + 2 * N_NODES};

    hipMemsetAsync(off, 0, zeroB, stream);

    // wtrans + frontier seed in one launch (sniff inlined per block)
    setup_kernel<<<44, 256, 0, stream>>>(W_gc, b_gc, W_bi, b_bi, vals, users, items,
                                         WT, sb, flagL[0], flagL[1], flagL[2]);

    // frontier: flag3 = batch; flag2 = flag3 ∪ 1hop; flag1 = flag2 ∪ 1hop(flag2)
    prop_kernel<<<EGRID8, 256, 0, stream>>>((const int4*)rows, (const int4*)cols, flagL[2], flagL[1]);
    prop_kernel<<<EGRID8, 256, 0, stream>>>((const int4*)rows, (const int4*)cols, flagL[1], flagL[0]);

    // flag1-filtered degree count; atomic return value = within-row rank (persisted)
    count_rank_kernel<<<EGRID8, 256, 0, stream>>>((const int4*)rows, flagL[0], off, rank);

    // fused scans: A = block sums + class counts (+cls); B13 = 13 parallel top-scans;
    // C = off scan + 12-level scatter (class bases folded in from vtot)
    scanA_kernel<<<NB, 256, 0, stream>>>(off, flags, bsum, bcnt, cls);
    scanB13_kernel<<<13, 256, 0, stream>>>(bsum, bcnt, vtot);
    scanC_kernel<<<NB, 256, 0, stream>>>(off, bsum, flags, cls, bcnt, vtot, lists, map3, cnts);

    // atomic-free CSR fill of flag1 rows (stores col<<6)
    fill_kernel<<<EGRID8, 256, 0, stream>>>((const int4*)rows, (const int4*)cols, vals, off, rank, epack);

    // layers: ego double-buffered (k=0 reads raw inputs, writes A; 1: A->B; 2: B->A)
    // 8192 one-wave blocks: finest scheduling granularity (R9: 52.0us on L0)
    fused_layer_kernel<1><<<8192, 64, 0, stream>>>(off, epack, egoA, user_emb, item_emb,
                                                   vals, WT, sb, 0, egoA,
                                                   listL[0], cnts + 0, map3, acc);
    fused_layer_kernel<0><<<8192, 64, 0, stream>>>(off, epack, egoA, user_emb, item_emb,
                                                   vals, WT, sb, 1, egoB2,
                                                   listL[1], cnts + 1, map3, acc);
    fused_layer_kernel<0><<<8192, 64, 0, stream>>>(off, epack, egoB2, user_emb, item_emb,
                                                   vals, WT, sb, 2, egoA,
                                                   listL[2], cnts + 2, map3, acc);
    dot_kernel<<<(BATCH * 64) / 256, 256, 0, stream>>>(users, items, acc, map3,
                                                       user_emb, item_emb, d_out, vals);
}

// Round 11
// 277.128 us; speedup vs baseline: 1.0118x; 1.0118x over previous
//
#include <hip/hip_runtime.h>
#include <hip/hip_bf16.h>

#define N_USERS 100000
#define M_ITEMS 200000
#define N_NODES 300000   // N_USERS + M_ITEMS
#define N_EDGES 1200000
#define BATCH   4096
#define NB      ((N_NODES + 255) / 256)   // 1172
#define CHUNK   5                          // ceil(NB/256)
#define EPT4    (N_EDGES / 4)              // 300000: 4 edges per thread
#define EGRID4  ((EPT4 + 255) / 256)       // 1172 blocks

typedef __attribute__((ext_vector_type(8))) short short8;
typedef __attribute__((ext_vector_type(4))) float floatx4;

static __device__ __forceinline__ float b2f(__hip_bfloat16 x) { return __bfloat162float(x); }

static __device__ __forceinline__ short f2bs(float f) {
    union { __hip_bfloat16 h; short s; } u;
    u.h = __float2bfloat16(f);   // RNE
    return u.s;
}
static __device__ __forceinline__ float us2f(unsigned int us) {
    return __uint_as_float(us << 16);
}

// dtype-adaptive input load: isbf chosen at runtime from device-side sniff
static __device__ __forceinline__ float loadf(const void* p, int i, int isbf) {
    if (isbf) return b2f(((const __hip_bfloat16*)p)[i]);
    return ((const float*)p)[i];
}

// vals is uniform[0,1). bf16 buffer: u16[even] upper byte in [0x3A,0x3F].
static __device__ __forceinline__ int sniff_dev(const void* vals) {
    const unsigned short* v16 = (const unsigned short*)vals;
    int c = 0;
#pragma unroll
    for (int i = 0; i < 16; ++i) {
        unsigned int ub = (v16[2 * i] >> 8) & 0xFF;
        if (ub >= 0x3A && ub <= 0x3F) ++c;
    }
    return (c >= 12) ? 1 : 0;
}

static __device__ __forceinline__ void unpack8(float* o, uint4 e) {
    unsigned int w[4] = {e.x, e.y, e.z, e.w};
#pragma unroll
    for (int j = 0; j < 8; ++j) o[j] = us2f((w[j >> 1] >> ((j & 1) * 16)) & 0xFFFFu);
}

// n64 = node*64 (premultiplied element offset)
static __device__ __forceinline__ const unsigned short* bfsrc(
    const void* ue, const void* ie, int n64) {
    return (n64 < N_USERS * 64)
        ? (const unsigned short*)ue + (size_t)(unsigned)n64
        : (const unsigned short*)ie + (size_t)(unsigned)(n64 - N_USERS * 64);
}
static __device__ __forceinline__ const float* fsrc(
    const void* ue, const void* ie, int n64) {
    return (n64 < N_USERS * 64)
        ? (const float*)ue + (size_t)(unsigned)n64
        : (const float*)ie + (size_t)(unsigned)(n64 - N_USERS * 64);
}

// 16 dims of a node row in A-fragment layout
static __device__ __forceinline__ void gather16o(
    float* o0, float* o1, const unsigned short* ego,
    const void* ue, const void* ie, int n64, int quad, int isbf, int use_src) {
    if (!use_src) {
        const unsigned short* p = ego + (size_t)(unsigned)n64 + quad * 8;
        unpack8(o0, *(const uint4*)p);
        unpack8(o1, *(const uint4*)(p + 32));
    } else if (isbf) {
        const unsigned short* p = bfsrc(ue, ie, n64) + quad * 8;
        unpack8(o0, *(const uint4*)p);
        unpack8(o1, *(const uint4*)(p + 32));
    } else {
        const float* p = fsrc(ue, ie, n64) + quad * 8;
        float4 a = *(const float4*)p;
        float4 b = *(const float4*)(p + 4);
        float4 c = *(const float4*)(p + 32);
        float4 d = *(const float4*)(p + 36);
        o0[0]=a.x; o0[1]=a.y; o0[2]=a.z; o0[3]=a.w; o0[4]=b.x; o0[5]=b.y; o0[6]=b.z; o0[7]=b.w;
        o1[0]=c.x; o1[1]=c.y; o1[2]=c.z; o1[3]=c.w; o1[4]=d.x; o1[5]=d.y; o1[6]=d.z; o1[7]=d.w;
    }
}

// ---------------- setup: wtrans (blocks 0..11) + frontier seed (blocks 12..43) ----------------
__global__ __launch_bounds__(256) void setup_kernel(
    const void* __restrict__ Wg, const void* __restrict__ bg,
    const void* __restrict__ Wb, const void* __restrict__ bb,
    const void* __restrict__ vals,
    const int* __restrict__ users, const int* __restrict__ items,
    unsigned short* __restrict__ WT, float* __restrict__ sb,
    unsigned char* __restrict__ f1, unsigned char* __restrict__ f2,
    unsigned char* __restrict__ f3) {
    if (blockIdx.x < 12) {
        int isbf = __builtin_amdgcn_readfirstlane(sniff_dev(vals));
        int t = blockIdx.x * 256 + threadIdx.x;
        if (t < 3072) {
            int lane = t & 63, h = (t >> 6) & 1, ct = (t >> 7) & 3, w = (t >> 9) & 1, k = t >> 10;
            int m = lane & 15, quad = lane >> 4;
            const void* Wsrc = w ? Wb : Wg;
#pragma unroll
            for (int j = 0; j < 8; ++j) {
                int kk = h * 32 + quad * 8 + j;
                WT[(size_t)(k * 1024 + w * 512 + ct * 128 + h * 64 + lane) * 8 + j] =
                    (unsigned short)f2bs(loadf(Wsrc, k * 4096 + kk * 64 + ct * 16 + m, isbf));
            }
        }
        if (t < 192) sb[t] = loadf(bg, t, isbf) + loadf(bb, t, isbf);
    } else {
        int i = (blockIdx.x - 12) * 256 + threadIdx.x;
        int n = -1;
        if (i < BATCH) n = users[i];
        else if (i < 2 * BATCH) n = N_USERS + items[i - BATCH];
        if (n >= 0) { f1[n] = 1; f2[n] = 1; f3[n] = 1; }
    }
}

// ---------------- frontier propagation (pure, no atomics; 4 edges/thread) ----------------
// Early-out: skip the cols4 load + stores when none of this thread's 4 rows hit
// (prop1 ~90% of threads skip; prop2 ~57%).
__global__ __launch_bounds__(256) void prop_kernel(
    const int4* __restrict__ rows4, const int4* __restrict__ cols4,
    const unsigned char* __restrict__ src, unsigned char* __restrict__ dst) {
    int t = blockIdx.x * 256 + threadIdx.x;
    if (t < EPT4) {
        int4 r = rows4[t];
        unsigned char s0 = src[r.x], s1 = src[r.y], s2 = src[r.z], s3 = src[r.w];
        if (s0 | s1 | s2 | s3) {
            int4 c = cols4[t];
            if (s0) dst[c.x] = 1;
            if (s1) dst[c.y] = 1;
            if (s2) dst[c.z] = 1;
            if (s3) dst[c.w] = 1;
        }
    }
}

// Degree count filtered by flag1 — atomic return value IS the within-row rank.
__global__ __launch_bounds__(256) void count_rank_kernel(
    const int4* __restrict__ rows4, const unsigned char* __restrict__ flag1,
    int* __restrict__ off, uint2* __restrict__ rank) {
    int t = blockIdx.x * 256 + threadIdx.x;
    if (t < EPT4) {
        int4 r = rows4[t];
        unsigned int k0 = 0xFFFFu, k1 = 0xFFFFu, k2 = 0xFFFFu, k3 = 0xFFFFu;
        if (flag1[r.x]) k0 = (unsigned int)atomicAdd(&off[r.x + 1], 1);
        if (flag1[r.y]) k1 = (unsigned int)atomicAdd(&off[r.y + 1], 1);
        if (flag1[r.z]) k2 = (unsigned int)atomicAdd(&off[r.z + 1], 1);
        if (flag1[r.w]) k3 = (unsigned int)atomicAdd(&off[r.w + 1], 1);
        rank[t] = make_uint2((k0 & 0xFFFFu) | (k1 << 16), (k2 & 0xFFFFu) | (k3 << 16));
    }
}

static __device__ __forceinline__ int deg_class(int d) {
    return d >= 16 ? 0 : d >= 8 ? 1 : d >= 4 ? 2 : 3;
}

// ---------------- fused scan A: per-block degree sums + 12-level class counts + cls bytes ----
// Class-mask restructure: 4 class ballots ONCE + 1 flag ballot per level
// (was 12 ballots / 24 syncs). Counts identical.
__global__ __launch_bounds__(256) void scanA_kernel(
    const int* __restrict__ off, const unsigned char* __restrict__ flags,
    int* __restrict__ bsum, int* __restrict__ bcnt, unsigned char* __restrict__ cls) {
    __shared__ int s[256];
    __shared__ int wc[4][4];   // [wave][class]
    int t = threadIdx.x;
    int n = blockIdx.x * 256 + t;
    bool ir = (n < N_NODES);
    int deg = ir ? off[n + 1] : 0;      // raw degrees (pre-scan)
    s[t] = deg;
    __syncthreads();
    for (int o = 128; o >= 1; o >>= 1) {
        if (t < o) s[t] += s[t + o];
        __syncthreads();
    }
    if (t == 0) bsum[blockIdx.x] = s[0];
    int c = deg_class(deg);
    if (ir) cls[n] = (unsigned char)c;   // cls persisted: scanC must not re-read off
    int lane = t & 63;
    int wid  = t >> 6;
    unsigned long long mc[4];
#pragma unroll
    for (int cc = 0; cc < 4; ++cc) mc[cc] = __ballot(ir && (c == cc));
#pragma unroll
    for (int L = 0; L < 3; ++L) {
        unsigned long long mf = __ballot(ir && flags[L * N_NODES + n]);
        if (lane == 0) {
#pragma unroll
            for (int cc = 0; cc < 4; ++cc) wc[wid][cc] = __popcll(mf & mc[cc]);
        }
        __syncthreads();
        if (t < 4)
            bcnt[(L * 4 + t) * NB + blockIdx.x] = wc[0][t] + wc[1][t] + wc[2][t] + wc[3][t];
        __syncthreads();
    }
}

// ---------------- parallel top-scans: 13 concurrent blocks ----------------
// Blocks 0..11: one class row of bcnt each (per-row positions from 0; totals -> vtot).
// Block 12: bsum (degree block sums).
__global__ __launch_bounds__(256) void scanB13_kernel(
    int* __restrict__ bsum, int* __restrict__ bcnt, int* __restrict__ vtot) {
    __shared__ int s[256];
    int t = threadIdx.x;
    int* A = (blockIdx.x < 12) ? (bcnt + (size_t)blockIdx.x * NB) : bsum;
    int base = t * CHUNK, loc = 0;
    for (int j = 0; j < CHUNK; ++j) { int i = base + j; if (i < NB) loc += A[i]; }
    s[t] = loc;
    __syncthreads();
    for (int o = 1; o < 256; o <<= 1) {
        int add = (t >= o) ? s[t - o] : 0;
        __syncthreads();
        s[t] += add;
        __syncthreads();
    }
    int run = (t == 0) ? 0 : s[t - 1];
    for (int j = 0; j < CHUNK; ++j) {
        int i = base + j;
        if (i < NB) { int tmp = A[i]; A[i] = run; run += tmp; }
    }
    if (blockIdx.x < 12 && t == 0) vtot[blockIdx.x] = s[255];
}

// ---------------- fused scan C: off scan + 12-level scatter (+ map3, cnts) ----------------
// Class base within level (vb) folded in from vtot; class-mask scatter (positions
// bit-identical to the per-(L,c) ballot version).
__global__ __launch_bounds__(256) void scanC_kernel(
    int* __restrict__ off, const int* __restrict__ bsum,
    const unsigned char* __restrict__ flags, const unsigned char* __restrict__ cls,
    const int* __restrict__ bcnt, const int* __restrict__ vtot,
    int* __restrict__ lists, int* __restrict__ map3, int* __restrict__ cnts) {
    __shared__ int s[256];
    __shared__ int wc[4][4];
    __shared__ int vb[12];
    int t = threadIdx.x;
    if (t < 12) {
        int L = t >> 2, c = t & 3;
        int b = 0;
        for (int cc = 0; cc < c; ++cc) b += vtot[L * 4 + cc];
        vb[t] = b;
    }
    if (blockIdx.x == 0 && t < 3)
        cnts[t] = vtot[t * 4] + vtot[t * 4 + 1] + vtot[t * 4 + 2] + vtot[t * 4 + 3];
    int n = blockIdx.x * 256 + t;
    bool ir = (n < N_NODES);
    s[t] = ir ? off[n + 1] : 0;
    __syncthreads();   // covers vb writes too
    for (int o = 1; o < 256; o <<= 1) {
        int add = (t >= o) ? s[t - o] : 0;
        __syncthreads();
        s[t] += add;
        __syncthreads();
    }
    if (ir) off[n + 1] = s[t] + bsum[blockIdx.x];
    int c = ir ? (int)cls[n] : 3;
    int lane = t & 63;
    int wid  = t >> 6;
    unsigned long long mc[4];
#pragma unroll
    for (int cc = 0; cc < 4; ++cc) mc[cc] = __ballot(ir && (c == cc));
    unsigned long long lt = (1ull << lane) - 1ull;
#pragma unroll
    for (int L = 0; L < 3; ++L) {
        bool fl = ir && flags[L * N_NODES + n];
        unsigned long long mf = __ballot(fl);
        if (lane == 0) {
#pragma unroll
            for (int cc = 0; cc < 4; ++cc) wc[wid][cc] = __popcll(mf & mc[cc]);
        }
        __syncthreads();
        if (fl) {
            int wpre = 0;
            for (int i = 0; i < wid; ++i) wpre += wc[i][c];
            int pos = bcnt[(L * 4 + c) * NB + blockIdx.x] + vb[L * 4 + c] + wpre
                    + __popcll(mf & mc[c] & lt);
            lists[L * N_NODES + pos] = n;
            if (L == 2) map3[n] = pos + 1;   // node -> compact batch-acc slot (+1; 0 = none)
        }
        __syncthreads();
    }
}

// ---------------- atomic-free fill: p = off[row] + rank[e]; stores col<<6 ----------------
__global__ __launch_bounds__(256) void fill_kernel(
    const int4* __restrict__ rows4, const int4* __restrict__ cols4,
    const void* __restrict__ vals, const int* __restrict__ off,
    const uint2* __restrict__ rank, int2* __restrict__ epack) {
    int isbf = __builtin_amdgcn_readfirstlane(sniff_dev(vals));
    int t = blockIdx.x * 256 + threadIdx.x;
    if (t < EPT4) {
        int4 r = rows4[t];
        int4 c = cols4[t];
        uint2 kk = rank[t];
        unsigned int k0 = kk.x & 0xFFFFu, k1 = kk.x >> 16;
        unsigned int k2 = kk.y & 0xFFFFu, k3 = kk.y >> 16;
        int e = t * 4;
        if (k0 != 0xFFFFu)
            epack[off[r.x] + (int)k0] = make_int2(c.x << 6, __float_as_int(loadf(vals, e, isbf)));
        if (k1 != 0xFFFFu)
            epack[off[r.y] + (int)k1] = make_int2(c.y << 6, __float_as_int(loadf(vals, e + 1, isbf)));
        if (k2 != 0xFFFFu)
            epack[off[r.z] + (int)k2] = make_int2(c.z << 6, __float_as_int(loadf(vals, e + 2, isbf)));
        if (k3 != 0xFFFFu)
            epack[off[r.w] + (int)k3] = make_int2(c.w << 6, __float_as_int(loadf(vals, e + 3, isbf)));
    }
}

// ---------------- Fused SpMM + Transform (per layer), no LDS ----------------
// Best-measured config (R9: 52.0us, VGPR 72, total 277.7us): 64-thread (1-wave)
// blocks, static interleaved tiles, NON-unrolled edge loop (compiler pipelines),
// PRELOADED B-fragments, self-gather at top. All probed alternatives regressed:
// x4 unroll (R2), wave cap (R3), ticket dispenser (R3/R4), register diet (R5),
// 8-edge sweeps + L0 acc-store (R10, null). L0 sits at the knob-invariant
// ~2 TB/s scattered-256B-granule plateau (R1/R2/R5/R8/R9/R10).
template<int USE_SRC>
__global__ __launch_bounds__(64) void fused_layer_kernel(
    const int* __restrict__ off, const int2* __restrict__ epack,
    const unsigned short* __restrict__ ego_in,
    const void* __restrict__ ue, const void* __restrict__ ie,
    const void* __restrict__ vals,
    const unsigned short* __restrict__ WT, const float* __restrict__ sb,
    int klayer, unsigned short* __restrict__ ego_out,
    const int* __restrict__ list, const int* __restrict__ cntp,
    const int* __restrict__ map3, float* __restrict__ acc) {
    const int isbf = USE_SRC ? __builtin_amdgcn_readfirstlane(sniff_dev(vals)) : 0;
    const int cnt  = __builtin_amdgcn_readfirstlane(cntp[0]);
    const int ntile = (cnt + 15) >> 4;
    const int wv = blockIdx.x;
    const int nw = gridDim.x;
    if (wv >= ntile) return;            // dead blocks exit before the prologue
    const int lane = threadIdx.x;
    const int m    = lane & 15;
    const int quad = lane >> 4;

    const unsigned short* wt = WT + (size_t)klayer * 8192;
    short8 Bg[4][2], Bb[4][2];
#pragma unroll
    for (int ct = 0; ct < 4; ++ct)
#pragma unroll
        for (int h = 0; h < 2; ++h) {
            Bg[ct][h] = *(const short8*)(wt + (size_t)((ct * 2 + h) * 64 + lane) * 8);
            Bb[ct][h] = *(const short8*)(wt + (size_t)(512 + (ct * 2 + h) * 64 + lane) * 8);
        }
    float bv[4];
#pragma unroll
    for (int ct = 0; ct < 4; ++ct) bv[ct] = sb[klayer * 64 + ct * 16 + m];

    for (int tile = wv; tile < ntile; tile += nw) {
        const int idx = tile * 16 + m;
        const int row = list[idx < cnt ? idx : cnt - 1];
        const int start = off[row];
        const int end   = off[row + 1];

        float eg0[8], eg1[8];
        gather16o(eg0, eg1, ego_in, ue, ie, row << 6, quad, isbf, USE_SRC);

        float s0[8] = {0,0,0,0,0,0,0,0};
        float s1[8] = {0,0,0,0,0,0,0,0};
        for (int e = start; e < end; ++e) {
            int2 cv = epack[e];
            float v = __int_as_float(cv.y);
            float t0[8], t1[8];
            gather16o(t0, t1, ego_in, ue, ie, cv.x, quad, isbf, USE_SRC);
#pragma unroll
            for (int j = 0; j < 8; ++j) {
                s0[j] = fmaf(v, t0[j], s0[j]);
                s1[j] = fmaf(v, t1[j], s1[j]);
            }
        }

        short8 As0, As1, Ap0, Ap1;
#pragma unroll
        for (int j = 0; j < 8; ++j) {
            As0[j] = f2bs(s0[j]);
            As1[j] = f2bs(s1[j]);
            Ap0[j] = f2bs(eg0[j] * s0[j]);
            Ap1[j] = f2bs(eg1[j] * s1[j]);
        }

        floatx4 accf[4];
#pragma unroll
        for (int ct = 0; ct < 4; ++ct) {
            floatx4 a = {0.f, 0.f, 0.f, 0.f};
            a = __builtin_amdgcn_mfma_f32_16x16x32_bf16(As0, Bg[ct][0], a, 0, 0, 0);
            a = __builtin_amdgcn_mfma_f32_16x16x32_bf16(As1, Bg[ct][1], a, 0, 0, 0);
            a = __builtin_amdgcn_mfma_f32_16x16x32_bf16(Ap0, Bb[ct][0], a, 0, 0, 0);
            a = __builtin_amdgcn_mfma_f32_16x16x32_bf16(Ap1, Bb[ct][1], a, 0, 0, 0);
            accf[ct] = a;
        }

        float v[4][4];
        float ssq[4] = {0.f, 0.f, 0.f, 0.f};
#pragma unroll
        for (int ct = 0; ct < 4; ++ct)
#pragma unroll
            for (int r = 0; r < 4; ++r) {
                float x = accf[ct][r] + bv[ct];
                x = x > 0.f ? x : 0.2f * x;           // leaky_relu(0.2)
                v[ct][r] = x;
                ssq[r] += x * x;
            }
#pragma unroll
        for (int o = 1; o < 16; o <<= 1)
#pragma unroll
            for (int r = 0; r < 4; ++r) ssq[r] += __shfl_xor(ssq[r], o, 64);
#pragma unroll
        for (int r = 0; r < 4; ++r) {
            int idx_w = tile * 16 + quad * 4 + r;
            if (idx_w < cnt) {
                float sc = 1.0f / fmaxf(sqrtf(ssq[r]), 1e-12f);
                int rw = list[idx_w];
                int c3 = map3[rw];
#pragma unroll
                for (int ct = 0; ct < 4; ++ct)
                    ego_out[(size_t)rw * 64 + ct * 16 + m] = (unsigned short)f2bs(v[ct][r] * sc);
                if (c3 > 0) {
                    float* ap = acc + (size_t)(c3 - 1) * 64 + m;
#pragma unroll
                    for (int ct = 0; ct < 4; ++ct) ap[ct * 16] += v[ct][r] * sc;
                }
            }
        }
    }
}

// out[b] = dot(acc_u + ego0_u, acc_i + ego0_i) / 16   (acc read via map3)
__global__ __launch_bounds__(256) void dot_kernel(
    const int* __restrict__ users, const int* __restrict__ items,
    const float* __restrict__ acc, const int* __restrict__ map3,
    const void* __restrict__ ue, const void* __restrict__ ie,
    void* __restrict__ out, const void* __restrict__ vals) {
    int isbf = __builtin_amdgcn_readfirstlane(sniff_dev(vals));
    int gid = blockIdx.x * 256 + threadIdx.x;
    int b = gid >> 6;
    int lane = gid & 63;
    int un = __builtin_amdgcn_readfirstlane(users[b]);
    int in_ = __builtin_amdgcn_readfirstlane(items[b]);
    int cu = __builtin_amdgcn_readfirstlane(map3[un]);
    int ci = __builtin_amdgcn_readfirstlane(map3[N_USERS + in_]);
    float u = (cu > 0 ? acc[(size_t)(cu - 1) * 64 + lane] : 0.f) + loadf(ue, un * 64 + lane, isbf);
    float v = (ci > 0 ? acc[(size_t)(ci - 1) * 64 + lane] : 0.f) + loadf(ie, in_ * 64 + lane, isbf);
    float pr = u * v;
#pragma unroll
    for (int o = 32; o >= 1; o >>= 1) pr += __shfl_xor(pr, o, 64);
    if (lane == 0) {
        float r = pr * 0.0625f;
        if (isbf) ((__hip_bfloat16*)out)[b] = __float2bfloat16(r);
        else      ((float*)out)[b] = r;
    }
}

static inline size_t align16(size_t x) { return (x + 15) & ~(size_t)15; }

extern "C" void kernel_launch(void* const* d_in, const int* in_sizes, int n_in,
                              void* d_out, int out_size, void* d_ws, size_t ws_size,
                              hipStream_t stream) {
    const int* users = (const int*)d_in[0];
    const int* items = (const int*)d_in[1];
    const int* rows  = (const int*)d_in[2];
    const int* cols  = (const int*)d_in[3];
    const void* vals     = d_in[4];
    const void* user_emb = d_in[5];
    const void* item_emb = d_in[6];
    const void* W_gc     = d_in[7];
    const void* b_gc     = d_in[8];
    const void* W_bi     = d_in[9];
    const void* b_bi     = d_in[10];

    const size_t egoB   = (size_t)N_NODES * 64 * sizeof(short);   // 38.4 MB (x2)
    const size_t packB  = (size_t)N_EDGES * sizeof(int2);         // 9.6 MB
    const size_t rankB  = (size_t)EPT4 * sizeof(uint2);           // 2.4 MB (4x u16 ranks)
    const size_t bsumB  = (size_t)NB * sizeof(int);
    const size_t bcntB  = (size_t)12 * NB * sizeof(int);          // 12 virtual levels
    const size_t clsB   = (size_t)N_NODES;                        // degree-class bytes
    const size_t wtB    = (size_t)3 * 1024 * 8 * sizeof(short);   // 49 KB
    const size_t sbB    = (size_t)192 * sizeof(float);
    const size_t accB   = (size_t)2 * BATCH * 64 * sizeof(float); // 2 MB (cnt3 <= 8192 slots)
    const size_t offB   = (size_t)(N_NODES + 1) * sizeof(int);
    const size_t cntsB  = (size_t)32 * sizeof(int);               // cnts(3) | vtot(12)@+4
    const size_t map3B  = (size_t)N_NODES * sizeof(int);
    const size_t flagsB = (size_t)3 * N_NODES;                    // 0.9 MB (bytes)

    char* ws = (char*)d_ws;
    size_t o = 0;
    unsigned short* egoA  = (unsigned short*)(ws + o); o += egoB;
    unsigned short* egoB2 = (unsigned short*)(ws + o); o += egoB;
    int2*  epack  = (int2*)(ws + o);  o += packB;
    uint2* rank   = (uint2*)(ws + o); o += rankB;
    int*   bsum   = (int*)(ws + o);   o += bsumB;
    int*   bcnt   = (int*)(ws + o);   o += bcntB;
    unsigned char* cls = (unsigned char*)(ws + o); o += clsB;
    o = align16(o);
    unsigned short* WT = (unsigned short*)(ws + o); o += wtB;
    float* sb     = (float*)(ws + o); o += sbB;
    // contiguous zero-region: acc | off | cnts(32) | map3 | flags(bytes)
    o = align16(o);
    float* acc    = (float*)(ws + o);
    int*   off    = (int*)((char*)acc + accB);
    int*   cnts   = (int*)((char*)off + offB);
    int*   vtot   = cnts + 4;
    int*   map3   = (int*)((char*)cnts + cntsB);
    unsigned char* flags = (unsigned char*)((char*)map3 + map3B);
    const size_t zeroB = accB + offB + cntsB + map3B + flagsB;
    unsigned char* flagL[3] = {flags, flags + N_NODES, flags + 2 * N_NODES};
    int* lists = (int*)(flags + flagsB);   // flagsB divisible by 4
    int* listL[3] = {lists, lists + N_NODES, lists + 2 * N_NODES};

    hipMemsetAsync(acc, 0, zeroB, stream);

    // wtrans + frontier seed in one launch (sniff inlined per block)
    setup_kernel<<<44, 256, 0, stream>>>(W_gc, b_gc, W_bi, b_bi, vals, users, items,
                                         WT, sb, flagL[0], flagL[1], flagL[2]);

    // frontier: flag3 = batch; flag2 = flag3 ∪ 1hop; flag1 = flag2 ∪ 1hop(flag2)
    prop_kernel<<<EGRID4, 256, 0, stream>>>((const int4*)rows, (const int4*)cols, flagL[2], flagL[1]);
    prop_kernel<<<EGRID4, 256, 0, stream>>>((const int4*)rows, (const int4*)cols, flagL[1], flagL[0]);

    // flag1-filtered degree count; atomic return value = within-row rank (persisted)
    count_rank_kernel<<<EGRID4, 256, 0, stream>>>((const int4*)rows, flagL[0], off, rank);

    // fused scans: A = block sums + class counts (+cls); B13 = 13 parallel top-scans;
    // C = off scan + 12-level scatter (class bases folded in from vtot)
    scanA_kernel<<<NB, 256, 0, stream>>>(off, flags, bsum, bcnt, cls);
    scanB13_kernel<<<13, 256, 0, stream>>>(bsum, bcnt, vtot);
    scanC_kernel<<<NB, 256, 0, stream>>>(off, bsum, flags, cls, bcnt, vtot, lists, map3, cnts);

    // atomic-free CSR fill of flag1 rows (stores col<<6)
    fill_kernel<<<EGRID4, 256, 0, stream>>>((const int4*)rows, (const int4*)cols, vals, off, rank, epack);

    // layers: ego double-buffered (k=0 reads raw inputs, writes A; 1: A->B; 2: B->A)
    // 8192 one-wave blocks: finest scheduling granularity (R9: 52.0us on L0)
    fused_layer_kernel<1><<<8192, 64, 0, stream>>>(off, epack, egoA, user_emb, item_emb,
                                                   vals, WT, sb, 0, egoA,
                                                   listL[0], cnts + 0, map3, acc);
    fused_layer_kernel<0><<<8192, 64, 0, stream>>>(off, epack, egoA, user_emb, item_emb,
                                                   vals, WT, sb, 1, egoB2,
                                                   listL[1], cnts + 1, map3, acc);
    fused_layer_kernel<0><<<8192, 64, 0, stream>>>(off, epack, egoB2, user_emb, item_emb,
                                                   vals, WT, sb, 2, egoA,
                                                   listL[2], cnts + 2, map3, acc);
    dot_kernel<<<(BATCH * 64) / 256, 256, 0, stream>>>(users, items, acc, map3,
                                                       user_emb, item_emb, d_out, vals);
}